// Round 2
// baseline (743.704 us; speedup 1.0000x reference)
//
#include <hip/hip_runtime.h>

// hidden = tanh(H @ h + C @ c); comm = hidden. H,C: [64,64]; h,c: [64, 524288].
#define NA 64
#define FD 524288
#define JT 8  // j-tile: 16 batched global loads in flight per tile

// One fp32 column per thread. acc[64] = 64 VGPR (vs 128 for the float2 version)
// -> __launch_bounds__(256,4) caps at 128 VGPR, ~4 waves/SIMD = 16 waves/CU
// (2x the old grid-limited 8/CU). Grid = 2048 blocks = 8 blocks/CU available.
//
// j-tiled so (a) 16 global loads issue back-to-back per tile (deep MLP per
// wave, vs 1-deep prefetch before), and (b) H/C are read ROW-contiguous per i
// (Hm[i*64 + jt..jt+7]) -> compiler emits s_load_dwordx8 instead of 128
// discrete stride-64 s_load_dword per j-step (16x less scalar-pipe issue).
__global__ __launch_bounds__(256, 4) void linlayer_kernel(
    const float* __restrict__ h, const float* __restrict__ c,
    const float* __restrict__ Hm, const float* __restrict__ Cm,
    float* __restrict__ out)
{
    const int d = blockIdx.x * blockDim.x + threadIdx.x;  // 0..524287

    const float* __restrict__ hp = h + d;
    const float* __restrict__ cp = c + d;

    float acc[NA];
#pragma unroll
    for (int i = 0; i < NA; ++i) acc[i] = 0.f;

#pragma unroll 1
    for (int jt = 0; jt < NA; jt += JT) {
        // Batched column loads for this j-tile: 16 loads in flight, coalesced
        // (lane i reads base + 4*i -> 256B/wave segments).
        float hv[JT], cv[JT];
#pragma unroll
        for (int jj = 0; jj < JT; ++jj) {
            hv[jj] = hp[(size_t)(jt + jj) * FD];
            cv[jj] = cp[(size_t)(jt + jj) * FD];
        }

        // FMA body: 64 i x 8 j x 2 mats = 1024 v_fmac_f32 per tile.
        // Hij/Cij are wave-uniform, row-contiguous -> s_load_dwordx8, and
        // v_fmac_f32 takes the SGPR directly (1 SGPR operand allowed).
#pragma unroll
        for (int i = 0; i < NA; ++i) {
            float a = acc[i];
#pragma unroll
            for (int jj = 0; jj < JT; ++jj) {
                a = fmaf(Hm[i * NA + jt + jj], hv[jj], a);
                a = fmaf(Cm[i * NA + jt + jj], cv[jj], a);
            }
            acc[i] = a;
        }
    }

    // Epilogue: tanh(x) = 1 - 2/(exp(2x)+1); saturates cleanly, no NaN.
    // Non-temporal stores: the 268 MB of output would otherwise evict the
    // 256 MB of inputs from Infinity Cache (counters show L3 currently
    // absorbs ~half the reads -- keep it that way).
    float* __restrict__ op = out + d;
#pragma unroll
    for (int i = 0; i < NA; ++i) {
        const float e = __expf(2.0f * acc[i]);
        const float t = 1.0f - 2.0f / (e + 1.0f);
        __builtin_nontemporal_store(t, &op[(size_t)i * FD]);        // hidden
        __builtin_nontemporal_store(t, &op[(size_t)(NA + i) * FD]); // comm
    }
}

extern "C" void kernel_launch(void* const* d_in, const int* in_sizes, int n_in,
                              void* d_out, int out_size, void* d_ws, size_t ws_size,
                              hipStream_t stream) {
    const float* h  = (const float*)d_in[0];
    const float* c  = (const float*)d_in[1];
    const float* Hm = (const float*)d_in[2];
    const float* Cm = (const float*)d_in[3];
    float* out = (float*)d_out;

    dim3 block(256);
    dim3 grid(FD / 256);  // 2048 blocks = 8 blocks/CU available
    hipLaunchKernelGGL(linlayer_kernel, grid, block, 0, stream,
                       h, c, Hm, Cm, out);
}